// Round 12
// baseline (325.319 us; speedup 1.0000x reference)
//
#include <hip/hip_runtime.h>

#define T_LEN 1024
#define P_DIM 32
#define HOME_IDX 0
#define FCH 192                 // forward chunk length (multiple of 4)
#define NROW 194                // 0..191 in-chunk slots + 2 alternating boundary slots
#define DHOFF (NROW * 32)       // float offset of delta0h log inside HB
#define NCHUNK 32               // backtrack chunks
#define CHUNK 32                // backtrack chunk length

// One wave (lanes 0-63) per batch runs the VALUE recurrence only; psi bytes
// are recomputed chunk-parallel by all 16 waves from a logged delta history.
//
// Key idea: psi[t] = f(delta[t-1], delta0h[t-1], A) is OFF the serial value
// chain. The forward wave logs delta[t] (+delta0h[t]) into LDS ring HB and
// skips the argmax scan / cross-half combine / psi write entirely (the ~50
// VALU instrs + 1 DS that r10/r11 carried per step). Every FCH steps, a
// barrier lets all 1024 threads recompute that chunk's psi bytes t-parallel
// (each (t,p) task: 8 uniform b128 reads + 32 adds + max3 tree + 31-step
// first-index scan). Recompute is bit-exact: c[q] and v0 are the same
// expressions on the same logged values; v1 is the same set-max (zero-sign
// irrelevant: only used in == and > comparisons); scan = proven r7 form.
//
// Forward per step (all 32 q's per lane, no cross-half split => NO shfl_xor):
//   c[q] = R[q] + Acol[q]; v1 = max3 tree (r7-proven text);
//   v0 = delta0h + Acol[0]; use1 = v1 > v0 strict; cond = use1 || is_home;
//   dn1 = (cond ? v1 : v0) + Ut; delta0h = (delta0h + A00) + u0c;
//   write HB slot ws (lane 32 diverts to the delta0h log — address/value
//   cndmask select, no exec divergence); 8 uniform b128 reads of slot ws
//   feed the NEXT step (r7/r10-proven in-order DS write->read, no barrier);
//   tail: Ut_n prep, u0 shfl (r4-proven), depth-4 global prefetch ring.
//
// Slot plan: chunk k (base a = k*FCH) writes s=1..191 -> slots 1..191 and
// s=192 -> slot 192+(k&1). Next chunk's first step consumes the just-read
// boundary slot via registers (reads issued at end of the boundary step).
// Recompute of chunk k reads rs = s-1 for s>=2; s==1 reads slot 0 (k==0,
// init-staged delta[0]) or 192+((k-1)&1). Alternating parity ensures chunk
// k+1's boundary write never clobbers the slot chunk k+1's recompute needs.
//
// Exactness notes (harness-verified across rounds):
//  * NEG = finfo(f32).min/4; NEG + A == NEG (ulp(NEG) >> |A|) -> v=0 slice
//    collapses to v0 = delta0h + A[0][p], a0 = 0 exactly.
//  * use1 strict; psi byte = (use1||is_home) ? (a1|32) : 0.
//  * delta0h update order preserved: (delta0h + A00) + (u[t,0] + bias0)
//    (u0c = lane 0's Ut, bias[0] == bias_p there).
//
// Backtrack (PROVEN round 4): phases 1-3 verbatim.

__launch_bounds__(1024, 1)
__global__ void crf_viterbi_kernel(const float* __restrict__ U,
                                   const float* __restrict__ A,
                                   const float* __restrict__ bias,
                                   int* __restrict__ out)
{
    __shared__ __align__(16) float HB[NROW * 32 + NROW];  // 25608 B: hist + dh
    __shared__ unsigned char spsi[(T_LEN - 1) * P_DIM];   // 32736 B
    __shared__ unsigned char Mmap[NCHUNK * P_DIM];
    __shared__ unsigned char ent[NCHUNK];
    __shared__ int last_p_sh;

    const int tid = threadIdx.x;
    const int b   = blockIdx.x;
    int* __restrict__ outb = out + (size_t)b * T_LEN;
    const float4* __restrict__ HB4 = (const float4*)HB;

    const int  p = tid & 31;
    const bool is_home = (p == HOME_IDX);

    // A column Acol[q] = A[q][p] — used by BOTH forward (tid<64) and recompute.
    float Acol[32];
#pragma unroll
    for (int q = 0; q < 32; ++q)
        Acol[q] = A[q * P_DIM + p];
    const float A00    = A[0];
    const float bias_p = bias[p];

    // Forward-wave state (meaningful only for tid<64; others never use it).
    float delta1 = 0.f, delta0h = 0.f;
    float L0 = 0.f, L1 = 0.f, L2 = 0.f, L3 = 0.f, Ut_n = 0.f, u0_n = 0.f;
    float4 R0, R1, R2, R3, R4, R5, R6, R7;
    const float* __restrict__ Ub = U + (size_t)b * T_LEN * P_DIM;

    if (tid < 64) {
        const float NEG = -(3.4028234663852886e38f / 4.0f);
        const float u00 = Ub[p] + bias_p;
        delta1  = is_home ? NEG : u00;        // v=1 slice, per-lane p
        delta0h = Ub[HOME_IDX] + bias[0];     // v=0 slice at HOME (uniform)

        L0 = Ub[1 * P_DIM + p];
        L1 = Ub[2 * P_DIM + p];
        L2 = Ub[3 * P_DIM + p];
        L3 = Ub[4 * P_DIM + p];
        Ut_n = L0 + bias_p;
        u0_n = __shfl(Ut_n, 0);

        // Stage slot 0 = delta[0] (+ delta0h[0]); issue first read set.
        const int wa = (tid == 32) ? (DHOFF + 0) : p;
        HB[wa] = (tid == 32) ? delta0h : delta1;
        R0 = HB4[0]; R1 = HB4[1]; R2 = HB4[2]; R3 = HB4[3];
        R4 = HB4[4]; R5 = HB4[5]; R6 = HB4[6]; R7 = HB4[7];
    }

#define STEP(t, ws, Lc, Lr) do {                                               \
    const float Ut  = Ut_n;                                                    \
    const float u0c = u0_n;                                                    \
    float c[32];                                                               \
    c[0]=R0.x+Acol[0];  c[1]=R0.y+Acol[1];  c[2]=R0.z+Acol[2];  c[3]=R0.w+Acol[3];   \
    c[4]=R1.x+Acol[4];  c[5]=R1.y+Acol[5];  c[6]=R1.z+Acol[6];  c[7]=R1.w+Acol[7];   \
    c[8]=R2.x+Acol[8];  c[9]=R2.y+Acol[9];  c[10]=R2.z+Acol[10]; c[11]=R2.w+Acol[11];\
    c[12]=R3.x+Acol[12]; c[13]=R3.y+Acol[13]; c[14]=R3.z+Acol[14]; c[15]=R3.w+Acol[15];\
    c[16]=R4.x+Acol[16]; c[17]=R4.y+Acol[17]; c[18]=R4.z+Acol[18]; c[19]=R4.w+Acol[19];\
    c[20]=R5.x+Acol[20]; c[21]=R5.y+Acol[21]; c[22]=R5.z+Acol[22]; c[23]=R5.w+Acol[23];\
    c[24]=R6.x+Acol[24]; c[25]=R6.y+Acol[25]; c[26]=R6.z+Acol[26]; c[27]=R6.w+Acol[27];\
    c[28]=R7.x+Acol[28]; c[29]=R7.y+Acol[29]; c[30]=R7.z+Acol[30]; c[31]=R7.w+Acol[31];\
    const float g0 = fmaxf(fmaxf(c[0],  c[1]),  c[2]);                         \
    const float g1 = fmaxf(fmaxf(c[3],  c[4]),  c[5]);                         \
    const float g2 = fmaxf(fmaxf(c[6],  c[7]),  c[8]);                         \
    const float g3 = fmaxf(fmaxf(c[9],  c[10]), c[11]);                        \
    const float g4 = fmaxf(fmaxf(c[12], c[13]), c[14]);                        \
    const float g5 = fmaxf(fmaxf(c[15], c[16]), c[17]);                        \
    const float g6 = fmaxf(fmaxf(c[18], c[19]), c[20]);                        \
    const float g7 = fmaxf(fmaxf(c[21], c[22]), c[23]);                        \
    const float g8 = fmaxf(fmaxf(c[24], c[25]), c[26]);                        \
    const float g9 = fmaxf(fmaxf(c[27], c[28]), c[29]);                        \
    const float m0 = fmaxf(fmaxf(g0, g1), g2);                                 \
    const float m1 = fmaxf(fmaxf(g3, g4), g5);                                 \
    const float m2 = fmaxf(fmaxf(g6, g7), g8);                                 \
    const float m3 = fmaxf(fmaxf(g9, c[30]), c[31]);                           \
    const float v1 = fmaxf(fmaxf(m0, m1), fmaxf(m2, m3));                      \
    const float v0 = delta0h + Acol[0];                                        \
    const bool  use1 = (v1 > v0);              /* strict, as reference */      \
    const bool  cond = use1 || is_home;                                        \
    const float sel  = cond ? v1 : v0;                                         \
    const float dn1  = sel + Ut;                                               \
    delta0h = (delta0h + A00) + u0c;                                           \
    /* log: lanes write dn1 to hist[ws][p]; lane 32 diverts to dh[ws] */       \
    const int wa_ = (tid == 32) ? (DHOFF + (ws)) : ((ws) * 32 + p);            \
    HB[wa_] = (tid == 32) ? delta0h : dn1;                                     \
    R0 = HB4[(ws)*8+0]; R1 = HB4[(ws)*8+1]; R2 = HB4[(ws)*8+2]; R3 = HB4[(ws)*8+3]; \
    R4 = HB4[(ws)*8+4]; R5 = HB4[(ws)*8+5]; R6 = HB4[(ws)*8+6]; R7 = HB4[(ws)*8+7]; \
    /* tail work overlaps the read latency */                                  \
    Ut_n = (Lc) + bias_p;                                                      \
    u0_n = __shfl(Ut_n, 0);                                                    \
    { int tn = (t) + 4; if (tn > T_LEN - 1) tn = T_LEN - 1;                    \
      (Lr) = Ub[(size_t)tn * P_DIM + p]; }                                     \
    delta1 = dn1;                                                              \
} while (0)

    for (int a = 0; a < T_LEN - 1; a += FCH) {
        const int ns   = (T_LEN - 1 - a < FCH) ? (T_LEN - 1 - a) : FCH;
        const int kpar = (a / FCH) & 1;

        if (tid < 64) {
            STEP(a + 1, 1, L1, L0);
            STEP(a + 2, 2, L2, L1);
            STEP(a + 3, 3, L3, L2);
            for (int s = 4; s + 3 <= ns; s += 4) {
                STEP(a + s + 0, s + 0, L0, L3);
                STEP(a + s + 1, s + 1, L1, L0);
                STEP(a + s + 2, s + 2, L2, L1);
                STEP(a + s + 3, s + 3, L3, L2);
            }
            if (ns == FCH)
                STEP(a + FCH, FCH + kpar, L0, L3);   // boundary slot 192/193
        }
        __syncthreads();   // history visible to all waves

        // psi recompute for t = a+1 .. a+ns, t-parallel across 1024 threads.
        {
            const int sg = tid >> 5;   // 0..31: which s-offset group
#pragma unroll
            for (int pass = 0; pass < FCH / 32; ++pass) {
                const int s = 1 + sg + 32 * pass;
                if (s <= ns) {
                    const int rs = (s == 1)
                        ? ((a == 0) ? 0 : (FCH + (kpar ^ 1)))
                        : (s - 1);
                    const float4 H0 = HB4[rs*8+0], H1 = HB4[rs*8+1];
                    const float4 H2 = HB4[rs*8+2], H3 = HB4[rs*8+3];
                    const float4 H4 = HB4[rs*8+4], H5 = HB4[rs*8+5];
                    const float4 H6 = HB4[rs*8+6], H7 = HB4[rs*8+7];
                    const float dhp = HB[DHOFF + rs];
                    float c[32];
                    c[0]=H0.x+Acol[0];  c[1]=H0.y+Acol[1];  c[2]=H0.z+Acol[2];  c[3]=H0.w+Acol[3];
                    c[4]=H1.x+Acol[4];  c[5]=H1.y+Acol[5];  c[6]=H1.z+Acol[6];  c[7]=H1.w+Acol[7];
                    c[8]=H2.x+Acol[8];  c[9]=H2.y+Acol[9];  c[10]=H2.z+Acol[10]; c[11]=H2.w+Acol[11];
                    c[12]=H3.x+Acol[12]; c[13]=H3.y+Acol[13]; c[14]=H3.z+Acol[14]; c[15]=H3.w+Acol[15];
                    c[16]=H4.x+Acol[16]; c[17]=H4.y+Acol[17]; c[18]=H4.z+Acol[18]; c[19]=H4.w+Acol[19];
                    c[20]=H5.x+Acol[20]; c[21]=H5.y+Acol[21]; c[22]=H5.z+Acol[22]; c[23]=H5.w+Acol[23];
                    c[24]=H6.x+Acol[24]; c[25]=H6.y+Acol[25]; c[26]=H6.z+Acol[26]; c[27]=H6.w+Acol[27];
                    c[28]=H7.x+Acol[28]; c[29]=H7.y+Acol[29]; c[30]=H7.z+Acol[30]; c[31]=H7.w+Acol[31];
                    const float g0 = fmaxf(fmaxf(c[0],  c[1]),  c[2]);
                    const float g1 = fmaxf(fmaxf(c[3],  c[4]),  c[5]);
                    const float g2 = fmaxf(fmaxf(c[6],  c[7]),  c[8]);
                    const float g3 = fmaxf(fmaxf(c[9],  c[10]), c[11]);
                    const float g4 = fmaxf(fmaxf(c[12], c[13]), c[14]);
                    const float g5 = fmaxf(fmaxf(c[15], c[16]), c[17]);
                    const float g6 = fmaxf(fmaxf(c[18], c[19]), c[20]);
                    const float g7 = fmaxf(fmaxf(c[21], c[22]), c[23]);
                    const float g8 = fmaxf(fmaxf(c[24], c[25]), c[26]);
                    const float g9 = fmaxf(fmaxf(c[27], c[28]), c[29]);
                    const float m0 = fmaxf(fmaxf(g0, g1), g2);
                    const float m1 = fmaxf(fmaxf(g3, g4), g5);
                    const float m2 = fmaxf(fmaxf(g6, g7), g8);
                    const float m3 = fmaxf(fmaxf(g9, c[30]), c[31]);
                    const float v1 = fmaxf(fmaxf(m0, m1), fmaxf(m2, m3));
                    const float v0 = dhp + Acol[0];
                    const bool use1 = (v1 > v0);
                    const bool cond = use1 || is_home;
                    int ia = 31;
#pragma unroll
                    for (int j = 30; j >= 0; --j)
                        if (c[j] == v1) ia = j;     // first (min) max index
                    spsi[(size_t)(a + s - 1) * P_DIM + p] =
                        (unsigned char)(cond ? (ia | 32) : 0);
                }
            }
        }
        __syncthreads();
    }
#undef STEP

    // last_p = argmax_p delta_T[:,1], first index wins (proven butterfly;
    // lanes 32..63 duplicate p = lane-32, idx tie-break handles them).
    if (tid < 64) {
        float mv = delta1;
        int   mi = p;
#pragma unroll
        for (int m = 16; m >= 1; m >>= 1) {
            float ov = __shfl_xor(mv, m);
            int   oi = __shfl_xor(mi, m);
            bool take = (ov > mv) || ((ov == mv) && (oi < mi));
            mv = take ? ov : mv;
            mi = take ? oi : mi;
        }
        if (tid == 0) {
            outb[T_LEN - 1] = mi;
            last_p_sh = mi;
        }
    }
    __syncthreads();

    // Phase 1: per-chunk maps (backtrack). Chunk c covers backsteps i in
    // [32c, min(32c+32, 1023)). Thread (c = tid>>5, pp = tid&31) walks from
    // hypothetical entry (pp, v=1).
    {
        const int c  = tid >> 5;
        const int pp = tid & 31;
        const int i_hi = min((c + 1) * CHUNK, T_LEN - 1);
        const int i_lo = c * CHUNK;
        int y = pp, v = 1;
        for (int i = i_hi - 1; i >= i_lo; --i) {
            const int bt = spsi[i * P_DIM + y];
            const int py = v ? (bt & 31) : 0;
            const int nv = v ? ((bt >> 5) & 1) : 0;
            y = py; v = nv;
        }
        Mmap[c * P_DIM + pp] = (unsigned char)(y | (v << 5));
    }
    __syncthreads();

    // Phase 2: compose maps from the top to get each chunk's true entry state.
    if (tid == 0) {
        int y = last_p_sh, v = 1;
        for (int c = NCHUNK - 1; c >= 0; --c) {
            ent[c] = (unsigned char)(y | (v << 5));
            if (v) {
                const int m = Mmap[c * P_DIM + y];
                y = m & 31;
                v = (m >> 5) & 1;
            } else {
                y = 0; v = 0;
            }
        }
    }
    __syncthreads();

    // Phase 3: 32 lanes re-walk their chunk from the true entry, emitting out.
    if (tid < NCHUNK) {
        const int c = tid;
        const int i_hi = min((c + 1) * CHUNK, T_LEN - 1);
        const int i_lo = c * CHUNK;
        const int e = ent[c];
        int y = e & 31;
        int v = (e >> 5) & 1;
        for (int i = i_hi - 1; i >= i_lo; --i) {
            const int bt = spsi[i * P_DIM + y];
            const int py = v ? (bt & 31) : 0;
            const int nv = v ? ((bt >> 5) & 1) : 0;
            outb[i] = py;
            y = py; v = nv;
        }
    }
}

extern "C" void kernel_launch(void* const* d_in, const int* in_sizes, int n_in,
                              void* d_out, int out_size, void* d_ws, size_t ws_size,
                              hipStream_t stream) {
    const float* U    = (const float*)d_in[0];   // (B, T, P) f32
    const float* A    = (const float*)d_in[1];   // (P, P)    f32
    const float* bias = (const float*)d_in[2];   // (P,)      f32
    int* out = (int*)d_out;                      // (B, T)    int32

    const int B = in_sizes[0] / (T_LEN * P_DIM);
    crf_viterbi_kernel<<<B, 1024, 0, stream>>>(U, A, bias, out);
}